// Round 1
// baseline (60.913 us; speedup 1.0000x reference)
//
#include <hip/hip_runtime.h>
#include <math.h>

#define DIM 16

// ---------------------------------------------------------------------------
// Precompute kernel: build A[4][16][16] = Re(U^dag Z_i U) into d_ws.
// U = StronglyEntanglingLayers(weights) as a 16x16 unitary, evolved column-
// by-column (16 threads, one column each) in double precision in LDS.
// ---------------------------------------------------------------------------
__global__ __launch_bounds__(256) void quanv_precompute(const float* __restrict__ w,
                                                        float* __restrict__ A) {
  __shared__ double Ur[DIM][DIM];  // [col j][amplitude m]
  __shared__ double Ui[DIM][DIM];
  const int tid = threadIdx.x;

  if (tid < DIM) {
    const int j = tid;
    for (int m = 0; m < DIM; ++m) {
      Ur[j][m] = (m == j) ? 1.0 : 0.0;
      Ui[j][m] = 0.0;
    }
    for (int l = 0; l < 2; ++l) {
      // Rot(phi, theta, omega) on each wire q (qubit 0 = MSB)
      for (int q = 0; q < 4; ++q) {
        double phi = (double)w[l * 12 + q * 3 + 0];
        double th  = (double)w[l * 12 + q * 3 + 1];
        double om  = (double)w[l * 12 + q * 3 + 2];
        double a  = 0.5 * (phi + om);
        double bb = 0.5 * (phi - om);
        double ct = cos(0.5 * th), st = sin(0.5 * th);
        // G = [[e^{-ia} ct, -e^{+ib} st], [e^{-ib} st, e^{+ia} ct]]
        double g00r =  cos(a) * ct, g00i = -sin(a) * ct;
        double g01r = -cos(bb) * st, g01i = -sin(bb) * st;
        double g10r =  cos(bb) * st, g10i = -sin(bb) * st;
        double g11r =  cos(a) * ct, g11i =  sin(a) * ct;
        const int bit = 1 << (3 - q);
        for (int m = 0; m < DIM; ++m) {
          if (m & bit) continue;
          const int m1 = m | bit;
          double v0r = Ur[j][m],  v0i = Ui[j][m];
          double v1r = Ur[j][m1], v1i = Ui[j][m1];
          Ur[j][m]  = g00r * v0r - g00i * v0i + g01r * v1r - g01i * v1i;
          Ui[j][m]  = g00r * v0i + g00i * v0r + g01r * v1i + g01i * v1r;
          Ur[j][m1] = g10r * v0r - g10i * v0i + g11r * v1r - g11i * v1i;
          Ui[j][m1] = g10r * v0i + g10i * v0r + g11r * v1i + g11i * v1r;
        }
      }
      // ring of CNOT(q, (q+r)%4), r = (l % 3) + 1, applied in order
      const int r = (l % 3) + 1;
      for (int q = 0; q < 4; ++q) {
        const int c = q, t = (q + r) & 3;
        const int cbit = 1 << (3 - c), tbit = 1 << (3 - t);
        for (int m = 0; m < DIM; ++m) {
          if ((m & cbit) && !(m & tbit)) {
            const int m1 = m | tbit;
            double tr = Ur[j][m]; Ur[j][m] = Ur[j][m1]; Ur[j][m1] = tr;
            double ti = Ui[j][m]; Ui[j][m] = Ui[j][m1]; Ui[j][m1] = ti;
          }
        }
      }
    }
  }
  __syncthreads();

  // A[i][j][k] = sum_m sign_i(m) * (Ur[j][m]*Ur[k][m] + Ui[j][m]*Ui[k][m])
  // sign_i(m) = +1 if bit (3-i) of m is 0 else -1   (<Z_i>, qubit 0 = MSB)
  for (int idx = tid; idx < 4 * DIM * DIM; idx += 256) {
    const int i = idx >> 8;
    const int j = (idx >> 4) & 15;
    const int k = idx & 15;
    double s = 0.0;
    for (int m = 0; m < DIM; ++m) {
      double term = Ur[j][m] * Ur[k][m] + Ui[j][m] * Ui[k][m];
      s += ((m >> (3 - i)) & 1) ? -term : term;
    }
    A[idx] = (float)s;
  }
}

// ---------------------------------------------------------------------------
// Main kernel: one thread per 2x2 patch.
//   psi = kron over qubits of [cos(t/2), sin(t/2)], t = tanh(pixel)*pi/2
//   out_i = psi^T A_i psi
// A reads are wave-uniform with compile-time offsets -> scalar loads.
// ---------------------------------------------------------------------------
__global__ __launch_bounds__(256) void quanv_main(const float* __restrict__ x,
                                                  const float* __restrict__ A,
                                                  float* __restrict__ out) {
  const int idx = blockIdx.x * 256 + threadIdx.x;   // 802816 threads exactly
  const int b   = idx / 12544;                      // 112*112
  const int rem = idx - b * 12544;
  const int i   = rem / 112;
  const int j   = rem - i * 112;

  const float* px = x + (size_t)b * 50176 + (size_t)(2 * i) * 224 + 2 * j;
  const float2 r0 = *(const float2*)(px);
  const float2 r1 = *(const float2*)(px + 224);

  const float HPI = 1.57079632679489662f;
  // qubit order: (row0,col0), (row0,col1), (row1,col0), (row1,col1)
  float t0 = tanhf(r0.x) * HPI;
  float t1 = tanhf(r0.y) * HPI;
  float t2 = tanhf(r1.x) * HPI;
  float t3 = tanhf(r1.y) * HPI;

  float c0, s0, c1, s1, c2, s2, c3, s3;
  __sincosf(0.5f * t0, &s0, &c0);
  __sincosf(0.5f * t1, &s1, &c1);
  __sincosf(0.5f * t2, &s2, &c2);
  __sincosf(0.5f * t3, &s3, &c3);

  // psi[m], m = b0 b1 b2 b3 (qubit 0 = MSB)
  float ab[4], cd[4], psi[16];
  ab[0] = c0 * c1; ab[1] = c0 * s1; ab[2] = s0 * c1; ab[3] = s0 * s1;
  cd[0] = c2 * c3; cd[1] = c2 * s3; cd[2] = s2 * c3; cd[3] = s2 * s3;
#pragma unroll
  for (int m = 0; m < 16; ++m) psi[m] = ab[m >> 2] * cd[m & 3];

  float o[4];
#pragma unroll
  for (int oi = 0; oi < 4; ++oi) {
    float acc = 0.0f;
#pragma unroll
    for (int jj = 0; jj < 16; ++jj) {
      float y = 0.0f;
#pragma unroll
      for (int kk = 0; kk < 16; ++kk)
        y = fmaf(A[oi * 256 + jj * 16 + kk], psi[kk], y);
      acc = fmaf(psi[jj], y, acc);
    }
    o[oi] = acc;
  }

  // out[b][oi][i][j], planes stride 12544
  float* po = out + (size_t)b * 4 * 12544 + (size_t)i * 112 + j;
  po[0 * 12544] = o[0];
  po[1 * 12544] = o[1];
  po[2 * 12544] = o[2];
  po[3 * 12544] = o[3];
}

extern "C" void kernel_launch(void* const* d_in, const int* in_sizes, int n_in,
                              void* d_out, int out_size, void* d_ws, size_t ws_size,
                              hipStream_t stream) {
  const float* x = (const float*)d_in[0];   // (64,1,224,224) f32
  const float* w = (const float*)d_in[1];   // (2,4,3) f32
  float* out = (float*)d_out;               // (64,4,112,112) f32
  float* A   = (float*)d_ws;                // 4*16*16 floats = 4 KiB

  quanv_precompute<<<1, 256, 0, stream>>>(w, A);
  quanv_main<<<3136, 256, 0, stream>>>(x, A, out);
}